// Round 4
// baseline (99.597 us; speedup 1.0000x reference)
//
#include <hip/hip_runtime.h>

#define B_DIM 256
#define IN_DIM 512
#define OUT_DIM 1024

typedef __attribute__((__ext_vector_type__(2))) float v2f;

// ---------- bit decode: [8] spike bits -> fp32 (exact E4M3 value) ----------
__device__ __forceinline__ float dec_pair(float4 a, float4 b) {
    int ef  = ((int)a.y << 3) | ((int)a.z << 2) | ((int)a.w << 1) | (int)b.x;
    int man = ((int)b.y << 2) | ((int)b.z << 1) | (int)b.w;
    float mag;
    if (ef > 0)
        mag = __uint_as_float(((unsigned)(ef + 120) << 23) | ((unsigned)man << 20));
    else
        mag = (float)man * 0.001953125f;  // man * 2^-9 (subnormal)
    return (a.x != 0.0f) ? -mag : mag;
}

// One dispatch decodes both x (v < 131072) and w (rest). Branch is uniform
// per block (131072 = 512 full blocks).
__global__ void k_decode(const float* __restrict__ xbits,
                         const float* __restrict__ wbits,
                         float* __restrict__ xf, float* __restrict__ wt) {
    int v = blockIdx.x * 256 + threadIdx.x;          // 0 .. 655359
    if (v < B_DIM * IN_DIM) {
        const float4* p = (const float4*)xbits + (size_t)v * 2;
        xf[v] = dec_pair(p[0], p[1]);
    } else {
        int u = v - B_DIM * IN_DIM;
        const float4* p = (const float4*)wbits + (size_t)u * 2;
        float val = dec_pair(p[0], p[1]);
        int o = u >> 9, i = u & 511;
        // wt layout [(i>>2)][o][i&3]: one coalesced dwordx4 per 4 K-steps in k_main
        wt[((size_t)(i >> 2) * OUT_DIM + o) * 4 + (i & 3)] = val;
    }
}

// ---------- encode fp32 (exact E4M3) -> [8] spike bits ----------
__device__ __forceinline__ void store8(float* __restrict__ out, int idx, float v) {
    unsigned au = __float_as_uint(v) & 0x7fffffffu;
    float sgn = (v < 0.0f) ? 1.0f : 0.0f;           // -0.0 -> sign bit 0, like ref
    int ef, man;
    if (au >= 0x3c800000u) {                         // |v| >= 2^-6 : normal
        ef  = (int)(au >> 23) - 120;                 // (exp-127)+7
        man = (int)((au >> 20) & 7u);
    } else {                                         // subnormal / zero
        ef  = 0;
        man = (int)(__uint_as_float(au) * 512.0f);   // exact multiple of 2^-9
    }
    float4 lo = make_float4(sgn,
                            (float)((ef >> 3) & 1), (float)((ef >> 2) & 1),
                            (float)((ef >> 1) & 1));
    float4 hi = make_float4((float)(ef & 1),
                            (float)((man >> 2) & 1), (float)((man >> 1) & 1),
                            (float)(man & 1));
    float4* op = (float4*)(out + (size_t)idx * 8);
    op[0] = lo;
    op[1] = hi;
}

// ---------- main sequential-quantized accumulation ----------
// grid (OUT/64, B/8), block 256 = 4 waves. lane -> o, wave -> 2 b-rows packed
// into one v2f chain. No LDS: x rows are wave-uniform (readfirstlane-forced)
// -> s_load scalar path, depth-2 SGPR pipeline. w: unconditional depth-4
// register prefetch (4-phase unrolled loop, overflow reads land in the huge
// workspace and are dead values). Per group: parallel product phase (8
// independent q(x*w)) then serial acc phase (add->cvt->unpk x8) — the
// product ops fill the acc chain's dependency-latency slots.
__global__ __launch_bounds__(256) void k_main(const float* __restrict__ xf,
                                              const float* __restrict__ wt,
                                              float* __restrict__ out) {
    int tid  = threadIdx.x;
    int lane = tid & 63;
    int wid  = tid >> 6;
    int o  = blockIdx.x * 64 + lane;
    int b0 = __builtin_amdgcn_readfirstlane(blockIdx.y * 8 + wid * 2);

    const float* xa = xf + (size_t)b0 * IN_DIM;      // SGPR-uniform pointer
    const float* xb = xa + IN_DIM;
    const float4* wq = (const float4*)wt + o;        // stride OUT_DIM f4 per i4

    v2f acc = {0.0f, 0.0f};                          // q(0 + p0) == p0: safe init

    // w prefetch slots: groups 0..3
    float4 wA[4], wB[4];
#pragma unroll
    for (int d = 0; d < 4; ++d) {
        wA[d] = wq[(size_t)(2 * d) * OUT_DIM];
        wB[d] = wq[(size_t)(2 * d + 1) * OUT_DIM];
    }
    // x prefetch slots (scalar/uniform): groups 0..1
    float xav[2][8], xbv[2][8];
#pragma unroll
    for (int d = 0; d < 2; ++d)
#pragma unroll
        for (int k = 0; k < 8; ++k) {
            xav[d][k] = xa[d * 8 + k];
            xbv[d][k] = xb[d * 8 + k];
        }

    for (int go = 0; go < 64; go += 4) {
#pragma unroll
        for (int ph = 0; ph < 4; ++ph) {
            int g = go + ph;
            float4 cwA = wA[ph], cwB = wB[ph];
            // prefetch w for g+4 into this slot (unconditional; tail reads
            // are within-allocation garbage, never consumed)
            wA[ph] = wq[(size_t)(2 * (g + 4)) * OUT_DIM];
            wB[ph] = wq[(size_t)(2 * (g + 4) + 1) * OUT_DIM];

            int xs = ph & 1;                          // x slot for group g
            float wk[8] = {cwA.x, cwA.y, cwA.z, cwA.w,
                           cwB.x, cwB.y, cwB.z, cwB.w};
            // ---- parallel product phase: pf[k] = q(x_k * w_k) ----
            v2f pf[8];
#pragma unroll
            for (int k = 0; k < 8; ++k) {
                v2f xp = {xav[xs][k], xbv[xs][k]};
                v2f wv = {wk[k], wk[k]};
                v2f p = xp * wv;
                int pq = __builtin_amdgcn_cvt_pk_fp8_f32(p.x, p.y, 0, false);
                pf[k] = __builtin_amdgcn_cvt_pk_f32_fp8(pq, false);
            }
            // ---- refill x slot with group g+2 (uniform s_load) ----
            {
                const float* nxa = xa + (size_t)(g + 2) * 8;
                const float* nxb = xb + (size_t)(g + 2) * 8;
#pragma unroll
                for (int k = 0; k < 8; ++k) {
                    xav[xs][k] = nxa[k];
                    xbv[xs][k] = nxb[k];
                }
            }
            // ---- serial acc phase: acc = q(acc + pf[k]) ----
#pragma unroll
            for (int k = 0; k < 8; ++k) {
                v2f s = acc + pf[k];
                int sq = __builtin_amdgcn_cvt_pk_fp8_f32(s.x, s.y, 0, false);
                acc = __builtin_amdgcn_cvt_pk_f32_fp8(sq, false);
            }
        }
    }

    store8(out, b0 * OUT_DIM + o, acc.x);
    store8(out, (b0 + 1) * OUT_DIM + o, acc.y);
}

extern "C" void kernel_launch(void* const* d_in, const int* in_sizes, int n_in,
                              void* d_out, int out_size, void* d_ws, size_t ws_size,
                              hipStream_t stream) {
    const float* xb = (const float*)d_in[0];   // [256][512][8]
    const float* wb = (const float*)d_in[1];   // [1024][512][8]
    float* out = (float*)d_out;                // [256][1024][8]

    float* xf = (float*)d_ws;                        // 131072 floats
    float* wt = (float*)d_ws + B_DIM * IN_DIM;       // 524288 floats
    // (prefetch tails read up to ~128 KB past wt end — ws is far larger)

    int total = B_DIM * IN_DIM + OUT_DIM * IN_DIM;   // 655360
    k_decode<<<dim3(total / 256), dim3(256), 0, stream>>>(xb, wb, xf, wt);

    dim3 grid(OUT_DIM / 64, B_DIM / 8);
    k_main<<<grid, dim3(256), 0, stream>>>(xf, wt, out);
}

// Round 5
// 98.255 us; speedup vs baseline: 1.0137x; 1.0137x over previous
//
#include <hip/hip_runtime.h>

#define B_DIM 256
#define IN_DIM 512
#define OUT_DIM 1024

typedef __attribute__((__ext_vector_type__(2))) float v2f;

// ---------- bit decode: [8] spike bits -> fp32 (exact E4M3 value) ----------
__device__ __forceinline__ float dec_pair(float4 a, float4 b) {
    int ef  = ((int)a.y << 3) | ((int)a.z << 2) | ((int)a.w << 1) | (int)b.x;
    int man = ((int)b.y << 2) | ((int)b.z << 1) | (int)b.w;
    float mag;
    if (ef > 0)
        mag = __uint_as_float(((unsigned)(ef + 120) << 23) | ((unsigned)man << 20));
    else
        mag = (float)man * 0.001953125f;  // man * 2^-9 (subnormal)
    return (a.x != 0.0f) ? -mag : mag;
}

// One dispatch decodes both x (v < 131072) and w (rest). Branch is uniform
// per block (131072 = 512 full blocks).
__global__ void k_decode(const float* __restrict__ xbits,
                         const float* __restrict__ wbits,
                         float* __restrict__ xf, float* __restrict__ wt) {
    int v = blockIdx.x * 256 + threadIdx.x;          // 0 .. 655359
    if (v < B_DIM * IN_DIM) {
        const float4* p = (const float4*)xbits + (size_t)v * 2;
        xf[v] = dec_pair(p[0], p[1]);
    } else {
        int u = v - B_DIM * IN_DIM;
        const float4* p = (const float4*)wbits + (size_t)u * 2;
        float val = dec_pair(p[0], p[1]);
        int o = u >> 9, i = u & 511;
        // wt layout [(i>>2)][o][i&3]: one coalesced dwordx4 per 4 K-steps in k_main
        wt[((size_t)(i >> 2) * OUT_DIM + o) * 4 + (i & 3)] = val;
    }
}

// ---------- encode fp32 (exact E4M3) -> [8] spike bits ----------
__device__ __forceinline__ void store8(float* __restrict__ out, int idx, float v) {
    unsigned au = __float_as_uint(v) & 0x7fffffffu;
    float sgn = (v < 0.0f) ? 1.0f : 0.0f;           // -0.0 -> sign bit 0, like ref
    int ef, man;
    if (au >= 0x3c800000u) {                         // |v| >= 2^-6 : normal
        ef  = (int)(au >> 23) - 120;                 // (exp-127)+7
        man = (int)((au >> 20) & 7u);
    } else {                                         // subnormal / zero
        ef  = 0;
        man = (int)(__uint_as_float(au) * 512.0f);   // exact multiple of 2^-9
    }
    float4 lo = make_float4(sgn,
                            (float)((ef >> 3) & 1), (float)((ef >> 2) & 1),
                            (float)((ef >> 1) & 1));
    float4 hi = make_float4((float)(ef & 1),
                            (float)((man >> 2) & 1), (float)((man >> 1) & 1),
                            (float)(man & 1));
    float4* op = (float4*)(out + (size_t)idx * 8);
    op[0] = lo;
    op[1] = hi;
}

// products for one group of 8 k-steps: pf[k] = q(xpair_k * w_k)
__device__ __forceinline__ void products8(v2f* pf, const float4* xc,
                                          float4 cwA, float4 cwB) {
    float wk[8] = {cwA.x, cwA.y, cwA.z, cwA.w, cwB.x, cwB.y, cwB.z, cwB.w};
    const v2f* xp = (const v2f*)xc;                  // 8 packed pairs
#pragma unroll
    for (int k = 0; k < 8; ++k) {
        v2f wv = {wk[k], wk[k]};
        v2f p = xp[k] * wv;                          // v_pk_mul_f32
        int pq = __builtin_amdgcn_cvt_pk_fp8_f32(p.x, p.y, 0, false);
        pf[k] = __builtin_amdgcn_cvt_pk_f32_fp8(pq, false);
    }
}

// ---------- main sequential-quantized accumulation ----------
// grid (B/8, OUT/64) -- b fastest so co-resident blocks share w in L2.
// block 256 = 4 waves; lane -> o, wave -> 2 b-rows packed into one v2f chain.
// x: one-time LDS stage (interleaved pairs), ds_read_b128 broadcast,
//    UNCONDITIONAL prefetch 1 group ahead (LDS padded for tail overread;
//    ds returns in-order -> compiler can use selective lgkmcnt).
// w: UNCONDITIONAL depth-4 register prefetch, 4-phase unrolled loop
//    (tail overreads land in the huge workspace; values dead).
// products pipelined 1 group ahead of the serial acc chain so ~24 independent
// VALU ops are always available to fill the add->cvt->unpk latency.
__global__ __launch_bounds__(256) void k_main(const float* __restrict__ xf,
                                              const float* __restrict__ wt,
                                              float* __restrict__ out) {
    __shared__ float xs[8 * IN_DIM + 32];            // +32: tail-overread pad
    int tid  = threadIdx.x;
    int lane = tid & 63;
    int wid  = tid >> 6;
    int o  = blockIdx.y * 64 + lane;
    int b0 = blockIdx.x * 8 + wid * 2;

    // ---- stage this wave's 2 x-rows as interleaved pairs ----
    {
        const float4* ra = (const float4*)(xf + (size_t)b0 * IN_DIM) + lane * 2;
        const float4* rb = (const float4*)(xf + (size_t)(b0 + 1) * IN_DIM) + lane * 2;
        float4 a0 = ra[0], a1 = ra[1];
        float4 c0 = rb[0], c1 = rb[1];
        float4* dst = (float4*)(xs + (size_t)wid * 2 * IN_DIM) + lane * 4;
        dst[0] = make_float4(a0.x, c0.x, a0.y, c0.y);
        dst[1] = make_float4(a0.z, c0.z, a0.w, c0.w);
        dst[2] = make_float4(a1.x, c1.x, a1.y, c1.y);
        dst[3] = make_float4(a1.z, c1.z, a1.w, c1.w);
    }
    __syncthreads();

    const float4* xls = (const float4*)(xs + (size_t)wid * 2 * IN_DIM);  // 256 f4
    const float4* wq  = (const float4*)wt + o;       // stride OUT_DIM f4 per i4

    v2f acc = {0.0f, 0.0f};                          // q(0 + p0) == p0: safe init

    // w slots hold groups 0..3
    float4 wA[4], wB[4];
#pragma unroll
    for (int d = 0; d < 4; ++d) {
        wA[d] = wq[(size_t)(2 * d) * OUT_DIM];
        wB[d] = wq[(size_t)(2 * d + 1) * OUT_DIM];
    }
    // x for group 0, then products(0), then x for group 1
    float4 xc0 = xls[0], xc1 = xls[1], xc2 = xls[2], xc3 = xls[3];
    v2f pf[8];
    {
        float4 xc[4] = {xc0, xc1, xc2, xc3};
        products8(pf, xc, wA[0], wB[0]);
    }
    xc0 = xls[4]; xc1 = xls[5]; xc2 = xls[6]; xc3 = xls[7];

    for (int go = 0; go < 64; go += 4) {
#pragma unroll
        for (int ph = 0; ph < 4; ++ph) {
            int g = go + ph;
            // products for group g+1 (xc holds g+1; w slot (ph+1)&3 holds g+1;
            // at g=63 this consumes garbage into a dead pf_next — harmless)
            v2f pf_next[8];
            {
                float4 xc[4] = {xc0, xc1, xc2, xc3};
                products8(pf_next, xc, wA[(ph + 1) & 3], wB[(ph + 1) & 3]);
            }
            // unconditional prefetches: w group g+4 into slot ph, x group g+2
            wA[ph] = wq[(size_t)(2 * (g + 4)) * OUT_DIM];
            wB[ph] = wq[(size_t)(2 * (g + 4) + 1) * OUT_DIM];
            {
                const float4* xn = xls + 4 * (g + 2);
                xc0 = xn[0]; xc1 = xn[1]; xc2 = xn[2]; xc3 = xn[3];
            }
            // serial acc phase for group g
#pragma unroll
            for (int k = 0; k < 8; ++k) {
                v2f s = acc + pf[k];                 // v_pk_add_f32
                int sq = __builtin_amdgcn_cvt_pk_fp8_f32(s.x, s.y, 0, false);
                acc = __builtin_amdgcn_cvt_pk_f32_fp8(sq, false);
            }
#pragma unroll
            for (int k = 0; k < 8; ++k) pf[k] = pf_next[k];
        }
    }

    store8(out, b0 * OUT_DIM + o, acc.x);
    store8(out, (b0 + 1) * OUT_DIM + o, acc.y);
}

extern "C" void kernel_launch(void* const* d_in, const int* in_sizes, int n_in,
                              void* d_out, int out_size, void* d_ws, size_t ws_size,
                              hipStream_t stream) {
    const float* xb = (const float*)d_in[0];   // [256][512][8]
    const float* wb = (const float*)d_in[1];   // [1024][512][8]
    float* out = (float*)d_out;                // [256][1024][8]

    float* xf = (float*)d_ws;                        // 131072 floats
    float* wt = (float*)d_ws + B_DIM * IN_DIM;       // 524288 floats
    // (w prefetch tail reads up to ~128 KB past wt end — ws is ~268 MB)

    int total = B_DIM * IN_DIM + OUT_DIM * IN_DIM;   // 655360
    k_decode<<<dim3(total / 256), dim3(256), 0, stream>>>(xb, wb, xf, wt);

    dim3 grid(B_DIM / 8, OUT_DIM / 64);
    k_main<<<grid, dim3(256), 0, stream>>>(xf, wt, out);
}